// Round 15
// baseline (156.199 us; speedup 1.0000x reference)
//
#include <hip/hip_runtime.h>
#include <math.h>

// FrequencyAwareHierarchicalEmbedding, MI355X/gfx950 — round 15
//
// B*L = 409600, D = 128, H = 32.
// d_in: fine_ids i32, coarse_ids i32, fine_W[1000001*128] f32,
//       coarse_W[10001*128] f32, freq_W[1000001] f32, W1[257*32], b1[32],
//       W2[32], b2[1].
// d_out: fused[BL*128] f32, then adjusted_gate[BL] f32.
//
// Round-15 = r13 structure + r14's LDS W1-fragment table (frees 32 persistent
// VGPRs) + r10's CROSS-TILE PREFETCH — this time with the register budget to
// afford it at launch_bounds(256,4) (peak live ~95 < 128 cap, no spill):
//  * prologue issues tile-0's 8 float4 gathers into fv[8] (32 VGPRs);
//  * per tile: pack fv->pk (fv dies) -> ds_write -> ISSUE tile t+1 gathers
//    into fv -> hc prefetch -> MFMA (B-frags from LDS) -> epilogue -> blend.
//    Next-tile gathers are in flight through ~1500cy of compute -> per-wave
//    memory-level parallelism ~2x.
//  * All components individually validated: float4 2-rows/instr (r13),
//    LDS fragment table (r14), pk-blend (r12), swizzled staging (r7+).
//  * launch_bounds(256,4); LDS 27KB.

#define DD 128
#define HH 32

typedef float  f32x4  __attribute__((ext_vector_type(4)));
typedef short  bf16x8 __attribute__((ext_vector_type(8)));

__device__ __forceinline__ float sigmoid_f(float x) {
    return 1.0f / (1.0f + expf(-x));
}

__device__ __forceinline__ unsigned short bf16_rne(float x) {
    union { float f; unsigned u; } c; c.f = x;
    unsigned u = c.u + 0x7fffu + ((c.u >> 16) & 1u);
    return (unsigned short)(u >> 16);
}

// ---------------------------------------------------------------- kernel A --
__global__ __launch_bounds__(256) void coarse_mlp_kernel(
    const float* __restrict__ coarse_W,
    const float* __restrict__ W1,
    const float* __restrict__ b1,
    float* __restrict__ hc,
    int nCoarse)
{
    const int t = blockIdx.x * 256 + threadIdx.x;
    if (t >= nCoarse * HH) return;
    const int r = t >> 5;
    const int j = t & 31;
    const float* __restrict__ row = coarse_W + (size_t)r * DD;
    const float* __restrict__ w   = W1 + DD * HH + j;   // coarse rows of W1
    float acc = b1[j];
    #pragma unroll 8
    for (int i = 0; i < DD; ++i)
        acc = fmaf(row[i], w[i * HH], acc);
    hc[t] = acc;
}

// ---------------------------------------------------------------- kernel B --
__global__ __launch_bounds__(256, 4) void fused_kernel(
    const int*   __restrict__ fine_ids,
    const int*   __restrict__ coarse_ids,
    const float* __restrict__ fine_W,
    const float* __restrict__ coarse_W,
    const float* __restrict__ freq_W,
    const float* __restrict__ W1,
    const float* __restrict__ W2,
    const float* __restrict__ b2,
    const float* __restrict__ hc,
    float* __restrict__ out_fused,
    float* __restrict__ out_gate)
{
    __shared__ __align__(16) unsigned int sX[4][1024];   // 16KB staging (4KB/wave)
    __shared__ __align__(16) unsigned int sW1f[2048];    // 8KB fragment table
    __shared__ float s_fw[256];
    __shared__ int   s_if[256];
    __shared__ int   s_ic[256];

    const int tid  = threadIdx.x;
    const int lane = tid & 63;
    const int wave = tid >> 6;
    const int P0   = (int)blockIdx.x * 256;

    const int jlo  = lane & 15;
    const int kg   = lane >> 4;         // 0..3
    const int l32  = lane & 31;         // col group for float4 row access
    const int hsel = lane >> 5;         // 0/1: which row of the pair

    // ---- metadata -------------------------------------------------------
    {
        const int p = P0 + tid;
        const int idf = fine_ids[p];
        s_if[tid] = idf;
        s_ic[tid] = coarse_ids[p];
        s_fw[tid] = sigmoid_f(freq_W[idf]);
    }

    // ---- build W1 fragment table in LDS (once; transient registers) -----
    #pragma unroll
    for (int n = 0; n < 2; ++n)
        #pragma unroll
        for (int ks = 0; ks < 4; ++ks) {
            bf16x8 t;
            #pragma unroll
            for (int i = 0; i < 8; ++i) {
                const int k = ks * 32 + kg * 8 + i;
                t[i] = (short)bf16_rne(W1[k * HH + jlo + 16 * n]);
            }
            *(bf16x8*)((char*)sW1f + (n * 4 + ks) * 1024 + lane * 16) = t;
        }

    // per-lane epilogue constants
    const float w256_0 = W1[2 * DD * HH + jlo];
    const float w256_1 = W1[2 * DD * HH + jlo + 16];
    const float W2_0   = W2[jlo];
    const float W2_1   = W2[jlo + 16];
    const float b2v    = b2[0];

    __syncthreads();    // fragment table + metadata ready (only barrier)

    char* const swave = (char*)&sX[wave][0];
    const int wbase = wave * 64;        // wave's first local position

    // ---- prologue: issue tile-0 gathers ---------------------------------
    float4 fv[8];
    #pragma unroll
    for (int i = 0; i < 8; ++i) {
        const int idf = s_if[wbase + 2 * i + hsel];
        fv[i] = *(const float4*)(fine_W + (size_t)idf * DD + 4 * l32);
    }

    // ---- main loop: 4 tiles of 16 rows, pipelined one tile ahead ---------
    #pragma unroll 1
    for (int it = 0; it < 4; ++it) {
        const int base = wbase + it * 16;

        // 1. pack current tile (waits on its vmcnt); fv regs die here
        unsigned pkA[8], pkB[8];
        #pragma unroll
        for (int i = 0; i < 8; ++i) {
            pkA[i] = (unsigned)bf16_rne(fv[i].x) | ((unsigned)bf16_rne(fv[i].y) << 16);
            pkB[i] = (unsigned)bf16_rne(fv[i].z) | ((unsigned)bf16_rne(fv[i].w) << 16);
        }

        // 2. swizzled ds_write (8B/lane per row pair)
        #pragma unroll
        for (int i = 0; i < 8; ++i) {
            const int row = 2 * i + hsel;
            uint2 w2; w2.x = pkA[i]; w2.y = pkB[i];
            *(uint2*)(swave + row * 256 + ((8 * l32) ^ ((row & 7) << 4))) = w2;
        }

        // 3. ISSUE next tile's gathers — in flight through MFMA/epilogue/blend
        if (it < 3) {
            #pragma unroll
            for (int i = 0; i < 8; ++i) {
                const int idf = s_if[base + 16 + 2 * i + hsel];
                fv[i] = *(const float4*)(fine_W + (size_t)idf * DD + 4 * l32);
            }
        }

        // 4. hc prefetch: issue before MFMA, consumed in the epilogue
        float hc0[4], hc1[4];
        #pragma unroll
        for (int r = 0; r < 4; ++r) {
            const int idc = s_ic[base + kg * 4 + r];
            const float* __restrict__ hcrow = hc + idc * HH;
            hc0[r] = hcrow[jlo];
            hc1[r] = hcrow[jlo + 16];
        }

        // 5. MFMA: X(16x128) @ W1fine(128x32); B-fragments from LDS table
        f32x4 acc0 = {0.f, 0.f, 0.f, 0.f};
        f32x4 acc1 = {0.f, 0.f, 0.f, 0.f};
        #pragma unroll
        for (int ks = 0; ks < 4; ++ks) {
            const bf16x8 a = *(const bf16x8*)(swave
                + jlo * 256 + ((kg * 16 + ks * 64) ^ ((jlo & 7) << 4)));
            const bf16x8 b0 = *(const bf16x8*)((char*)sW1f + ks * 1024 + lane * 16);
            const bf16x8 b1 = *(const bf16x8*)((char*)sW1f + (4 + ks) * 1024 + lane * 16);
            acc0 = __builtin_amdgcn_mfma_f32_16x16x32_bf16(a, b0, acc0, 0, 0, 0);
            acc1 = __builtin_amdgcn_mfma_f32_16x16x32_bf16(a, b1, acc1, 0, 0, 0);
        }

        // 6. epilogue: + hc + freq row, relu, @W2, butterfly, sigmoid
        float adjv[4];
        #pragma unroll
        for (int r = 0; r < 4; ++r) {
            const int posl = base + kg * 4 + r;
            const float fw = s_fw[posl];
            const float v0 = acc0[r] + hc0[r] + w256_0 * fw;
            const float v1 = acc1[r] + hc1[r] + w256_1 * fw;
            float tr = fmaxf(v0, 0.f) * W2_0 + fmaxf(v1, 0.f) * W2_1;
            tr += __shfl_xor(tr, 1);
            tr += __shfl_xor(tr, 2);
            tr += __shfl_xor(tr, 4);
            tr += __shfl_xor(tr, 8);
            adjv[r] = sigmoid_f(tr + b2v) * fw;       // uniform across jlo group
            if (jlo == r)
                __builtin_nontemporal_store(adjv[r], out_gate + P0 + posl);
        }

        // 7. blend from pk (bf16 fine) + coarse float4, 2 rows per instr
        #pragma unroll
        for (int i = 0; i < 8; ++i) {
            const int m0 = 2 * i, m1 = 2 * i + 1;
            const float a0 = __shfl(adjv[m0 & 3], (m0 >> 2) << 4);
            const float a1 = __shfl(adjv[m1 & 3], (m1 >> 2) << 4);
            const float a  = hsel ? a1 : a0;
            const int row  = base + 2 * i + hsel;
            const int idc  = s_ic[row];
            const float4 c4 = *(const float4*)(coarse_W + (size_t)idc * DD + 4 * l32);
            const float fx = __uint_as_float(pkA[i] << 16);
            const float fy = __uint_as_float(pkA[i] & 0xffff0000u);
            const float fz = __uint_as_float(pkB[i] << 16);
            const float fw4 = __uint_as_float(pkB[i] & 0xffff0000u);
            f32x4 o;
            o.x = fmaf(a, fx  - c4.x, c4.x);
            o.y = fmaf(a, fy  - c4.y, c4.y);
            o.z = fmaf(a, fz  - c4.z, c4.z);
            o.w = fmaf(a, fw4 - c4.w, c4.w);
            f32x4* dst = (f32x4*)(out_fused + (size_t)(P0 + row) * DD + 4 * l32);
            __builtin_nontemporal_store(o, dst);      // 1KB/instr, coalesced
        }
    }
}

// ------------------------------------------------------------------- launch --
extern "C" void kernel_launch(void* const* d_in, const int* in_sizes, int n_in,
                              void* d_out, int out_size, void* d_ws, size_t ws_size,
                              hipStream_t stream) {
    const int*   fine_ids   = (const int*)  d_in[0];
    const int*   coarse_ids = (const int*)  d_in[1];
    const float* fine_W     = (const float*)d_in[2];
    const float* coarse_W   = (const float*)d_in[3];
    const float* freq_W     = (const float*)d_in[4];
    const float* W1         = (const float*)d_in[5];
    const float* b1         = (const float*)d_in[6];
    const float* W2         = (const float*)d_in[7];
    const float* b2         = (const float*)d_in[8];

    const int n       = in_sizes[0];          // B*L = 409600 (divisible by 256)
    const int nCoarse = in_sizes[3] / DD;     // 10001

    float* out_fused = (float*)d_out;
    float* out_gate  = (float*)d_out + (size_t)n * DD;
    float* hc        = (float*)d_ws;          // nCoarse*32 floats = 1.28 MB

    coarse_mlp_kernel<<<dim3((nCoarse * HH + 255) / 256), dim3(256), 0, stream>>>(
        coarse_W, W1, b1, hc, nCoarse);

    fused_kernel<<<dim3(n / 256), dim3(256), 0, stream>>>(
        fine_ids, coarse_ids, fine_W, coarse_W, freq_W,
        W1, W2, b2, hc, out_fused, out_gate);
}

// Round 16
// 125.845 us; speedup vs baseline: 1.2412x; 1.2412x over previous
//
#include <hip/hip_runtime.h>
#include <math.h>

// FrequencyAwareHierarchicalEmbedding, MI355X/gfx950 — round 16
//
// B*L = 409600, D = 128, H = 32.
// d_in: fine_ids i32, coarse_ids i32, fine_W[1000001*128] f32,
//       coarse_W[10001*128] f32, freq_W[1000001] f32, W1[257*32], b1[32],
//       W2[32], b2[1].
// d_out: fused[BL*128] f32, then adjusted_gate[BL] f32.
//
// Round-16 = EXACT round-13 code (119.8us; r9/r12/r13 all ~119 = plateau)
// with ONE zero-register-cost change:
//  * NON-TEMPORAL fine-row loads. The fine gather streams 210MB through the
//    4MB/XCD L2 with no L2-lifetime reuse, evicting the structures that DO
//    reuse L2 (coarse rows: 5MB table re-read 210MB-worth; hc: 1.3MB; ids).
//    __builtin_nontemporal_load marks them evict-first, preserving L2 for
//    coarse/hc. Costs zero registers/instructions.
//  * Ledger: ILP-prefetch spills (r10/r15), TLP+25% neutral (r14), VMEM
//    instr count halved neutral (r13), headroom neutral (r12) -> memory-
//    system-bound; this is the last zero-pressure traffic-quality lever.
//  * Retained: single-pass barrier-free wave-private structure, float4
//    2-rows/instr access, hc prefetch, W1 B-fragments in 32 VGPRs,
//    XOR-swizzled staging, pk-blend, shfl_xor butterfly, nt stores,
//    launch_bounds(256,4).

#define DD 128
#define HH 32

typedef float  f32x4  __attribute__((ext_vector_type(4)));
typedef short  bf16x8 __attribute__((ext_vector_type(8)));

__device__ __forceinline__ float sigmoid_f(float x) {
    return 1.0f / (1.0f + expf(-x));
}

__device__ __forceinline__ unsigned short bf16_rne(float x) {
    union { float f; unsigned u; } c; c.f = x;
    unsigned u = c.u + 0x7fffu + ((c.u >> 16) & 1u);
    return (unsigned short)(u >> 16);
}

// ---------------------------------------------------------------- kernel A --
__global__ __launch_bounds__(256) void coarse_mlp_kernel(
    const float* __restrict__ coarse_W,
    const float* __restrict__ W1,
    const float* __restrict__ b1,
    float* __restrict__ hc,
    int nCoarse)
{
    const int t = blockIdx.x * 256 + threadIdx.x;
    if (t >= nCoarse * HH) return;
    const int r = t >> 5;
    const int j = t & 31;
    const float* __restrict__ row = coarse_W + (size_t)r * DD;
    const float* __restrict__ w   = W1 + DD * HH + j;   // coarse rows of W1
    float acc = b1[j];
    #pragma unroll 8
    for (int i = 0; i < DD; ++i)
        acc = fmaf(row[i], w[i * HH], acc);
    hc[t] = acc;
}

// ---------------------------------------------------------------- kernel B --
__global__ __launch_bounds__(256, 4) void fused_kernel(
    const int*   __restrict__ fine_ids,
    const int*   __restrict__ coarse_ids,
    const float* __restrict__ fine_W,
    const float* __restrict__ coarse_W,
    const float* __restrict__ freq_W,
    const float* __restrict__ W1,
    const float* __restrict__ W2,
    const float* __restrict__ b2,
    const float* __restrict__ hc,
    float* __restrict__ out_fused,
    float* __restrict__ out_gate)
{
    __shared__ __align__(16) unsigned int sX[4][1024];  // 4KB per wave, private
    __shared__ float s_fw[256];
    __shared__ int   s_if[256];
    __shared__ int   s_ic[256];

    const int tid  = threadIdx.x;
    const int lane = tid & 63;
    const int wave = tid >> 6;
    const int P0   = (int)blockIdx.x * 256;

    const int jlo  = lane & 15;
    const int kg   = lane >> 4;         // 0..3
    const int l32  = lane & 31;         // col group for float4 row access
    const int hsel = lane >> 5;         // 0/1: which row of the pair

    // ---- metadata (each wave writes & later reads ONLY its own 64 slots) --
    {
        const int p = P0 + tid;
        const int idf = fine_ids[p];
        s_if[tid] = idf;
        s_ic[tid] = coarse_ids[p];
        s_fw[tid] = sigmoid_f(freq_W[idf]);
    }

    // ---- W1 fine-half B-fragments -> 32 VGPRs, held all kernel ----------
    bf16x8 bfr[2][4];
    #pragma unroll
    for (int n = 0; n < 2; ++n)
        #pragma unroll
        for (int ks = 0; ks < 4; ++ks)
            #pragma unroll
            for (int i = 0; i < 8; ++i) {
                const int k = ks * 32 + kg * 8 + i;
                bfr[n][ks][i] = (short)bf16_rne(W1[k * HH + jlo + 16 * n]);
            }

    // per-lane epilogue constants
    const float w256_0 = W1[2 * DD * HH + jlo];
    const float w256_1 = W1[2 * DD * HH + jlo + 16];
    const float W2_0   = W2[jlo];
    const float W2_1   = W2[jlo + 16];
    const float b2v    = b2[0];

    char* const swave = (char*)&sX[wave][0];
    const int wbase = wave * 64;        // wave's first local position

    // ---- main loop: 4 tiles of 16 rows, fully wave-independent ----------
    #pragma unroll 1
    for (int it = 0; it < 4; ++it) {
        const int base = wbase + it * 16;

        // 1. load 16 fine rows as float4, 2 rows per instruction, NON-TEMPORAL
        //    (zero-reuse stream: keep L2 for coarse/hc), pack to bf16
        unsigned pkA[8], pkB[8];
        #pragma unroll
        for (int i = 0; i < 8; ++i) {
            const int idf = s_if[base + 2 * i + hsel];
            const f32x4* src = (const f32x4*)(fine_W + (size_t)idf * DD + 4 * l32);
            const f32x4 v = __builtin_nontemporal_load(src);
            pkA[i] = (unsigned)bf16_rne(v.x) | ((unsigned)bf16_rne(v.y) << 16);
            pkB[i] = (unsigned)bf16_rne(v.z) | ((unsigned)bf16_rne(v.w) << 16);
        }

        // 2. swizzled ds_write (8B per lane per pair; swizzle flips only
        //    byte bits 4-6, 8B alignment preserved)
        #pragma unroll
        for (int i = 0; i < 8; ++i) {
            const int row = 2 * i + hsel;
            uint2 w2; w2.x = pkA[i]; w2.y = pkB[i];
            *(uint2*)(swave + row * 256 + ((8 * l32) ^ ((row & 7) << 4))) = w2;
        }

        // 3. hc PREFETCH: issue before MFMA, consumed in the epilogue
        float hc0[4], hc1[4];
        #pragma unroll
        for (int r = 0; r < 4; ++r) {
            const int idc = s_ic[base + kg * 4 + r];
            const float* __restrict__ hcrow = hc + idc * HH;
            hc0[r] = hcrow[jlo];
            hc1[r] = hcrow[jlo + 16];
        }

        // 4. MFMA: X(16x128) @ W1fine(128x32)
        f32x4 acc0 = {0.f, 0.f, 0.f, 0.f};
        f32x4 acc1 = {0.f, 0.f, 0.f, 0.f};
        #pragma unroll
        for (int ks = 0; ks < 4; ++ks) {
            const bf16x8 a = *(const bf16x8*)(swave
                + jlo * 256 + ((kg * 16 + ks * 64) ^ ((jlo & 7) << 4)));
            acc0 = __builtin_amdgcn_mfma_f32_16x16x32_bf16(a, bfr[0][ks], acc0, 0, 0, 0);
            acc1 = __builtin_amdgcn_mfma_f32_16x16x32_bf16(a, bfr[1][ks], acc1, 0, 0, 0);
        }

        // 5. epilogue: + hc + freq row, relu, @W2, butterfly, sigmoid
        float adjv[4];
        #pragma unroll
        for (int r = 0; r < 4; ++r) {
            const int posl = base + kg * 4 + r;
            const float fw = s_fw[posl];
            const float v0 = acc0[r] + hc0[r] + w256_0 * fw;
            const float v1 = acc1[r] + hc1[r] + w256_1 * fw;
            float tr = fmaxf(v0, 0.f) * W2_0 + fmaxf(v1, 0.f) * W2_1;
            tr += __shfl_xor(tr, 1);
            tr += __shfl_xor(tr, 2);
            tr += __shfl_xor(tr, 4);
            tr += __shfl_xor(tr, 8);
            adjv[r] = sigmoid_f(tr + b2v) * fw;       // uniform across jlo group
            if (jlo == r)
                __builtin_nontemporal_store(adjv[r], out_gate + P0 + posl);
        }

        // 6. blend from pk (bf16 fine) + coarse float4, 2 rows per instr
        #pragma unroll
        for (int i = 0; i < 8; ++i) {
            const int m0 = 2 * i, m1 = 2 * i + 1;
            const float a0 = __shfl(adjv[m0 & 3], (m0 >> 2) << 4);
            const float a1 = __shfl(adjv[m1 & 3], (m1 >> 2) << 4);
            const float a  = hsel ? a1 : a0;
            const int row  = base + 2 * i + hsel;
            const int idc  = s_ic[row];
            const float4 c4 = *(const float4*)(coarse_W + (size_t)idc * DD + 4 * l32);
            const float fx = __uint_as_float(pkA[i] << 16);
            const float fy = __uint_as_float(pkA[i] & 0xffff0000u);
            const float fz = __uint_as_float(pkB[i] << 16);
            const float fw4 = __uint_as_float(pkB[i] & 0xffff0000u);
            f32x4 o;
            o.x = fmaf(a, fx  - c4.x, c4.x);
            o.y = fmaf(a, fy  - c4.y, c4.y);
            o.z = fmaf(a, fz  - c4.z, c4.z);
            o.w = fmaf(a, fw4 - c4.w, c4.w);
            f32x4* dst = (f32x4*)(out_fused + (size_t)(P0 + row) * DD + 4 * l32);
            __builtin_nontemporal_store(o, dst);      // 1KB/instr, coalesced
        }
    }
}

// ------------------------------------------------------------------- launch --
extern "C" void kernel_launch(void* const* d_in, const int* in_sizes, int n_in,
                              void* d_out, int out_size, void* d_ws, size_t ws_size,
                              hipStream_t stream) {
    const int*   fine_ids   = (const int*)  d_in[0];
    const int*   coarse_ids = (const int*)  d_in[1];
    const float* fine_W     = (const float*)d_in[2];
    const float* coarse_W   = (const float*)d_in[3];
    const float* freq_W     = (const float*)d_in[4];
    const float* W1         = (const float*)d_in[5];
    const float* b1         = (const float*)d_in[6];
    const float* W2         = (const float*)d_in[7];
    const float* b2         = (const float*)d_in[8];

    const int n       = in_sizes[0];          // B*L = 409600 (divisible by 256)
    const int nCoarse = in_sizes[3] / DD;     // 10001

    float* out_fused = (float*)d_out;
    float* out_gate  = (float*)d_out + (size_t)n * DD;
    float* hc        = (float*)d_ws;          // nCoarse*32 floats = 1.28 MB

    coarse_mlp_kernel<<<dim3((nCoarse * HH + 255) / 256), dim3(256), 0, stream>>>(
        coarse_W, W1, b1, hc, nCoarse);

    fused_kernel<<<dim3(n / 256), dim3(256), 0, stream>>>(
        fine_ids, coarse_ids, fine_W, coarse_W, freq_W,
        W1, W2, b2, hc, out_fused, out_gate);
}

// Round 17
// 117.827 us; speedup vs baseline: 1.3257x; 1.0680x over previous
//
#include <hip/hip_runtime.h>
#include <math.h>

// FrequencyAwareHierarchicalEmbedding, MI355X/gfx950 — round 17
// = EXACT round-9 kernel (118.6us, measured best across r9-r16).
//
// B*L = 409600, D = 128, H = 32.
// d_in: fine_ids i32, coarse_ids i32, fine_W[1000001*128] f32,
//       coarse_W[10001*128] f32, freq_W[1000001] f32, W1[257*32], b1[32],
//       W2[32], b2[1].
// d_out: fused[BL*128] f32, then adjusted_gate[BL] f32.
//
// Final structure:
//  * hc precompute (kernel A): coarse half of MLP1 folded per coarse-row
//    (exact f32), 10001x32 table in d_ws — halves per-position MLP FLOPs and
//    removes the coarse gather from the gate path.
//  * Fused kernel (B), single-pass, barrier-free, wave-private:
//    - fine rows loaded ONCE (f32, coalesced float2/lane), used for bf16 MFMA
//      staging AND the exact-f32 blend;
//    - MLP1 fine-half on MFMA 16x16x32_bf16, W1 B-fragments held in 32 VGPRs
//      all kernel; XOR-swizzled wave-private LDS staging (conflict-free);
//    - epilogue: +hc +freq-feature, relu, @W2 via 16-lane shfl_xor butterfly,
//      sigmoid; adj broadcast by compile-time-lane shfl;
//    - blend + nontemporal stores (1KB/row, coalesced).
//  * launch_bounds(256,4): 4 blocks/CU. Lever ledger (r10-r16): ILP-prefetch
//    spills, +25% TLP neutral, VMEM-count neutral, headroom neutral, nt-loads
//    negative -> memory-system equilibrium at ~3.4 TB/s effective on the
//    random-512B-gather + streaming-write mix (compulsory ~400MB -> ~119us).

#define DD 128
#define HH 32

typedef float  f32x2  __attribute__((ext_vector_type(2)));
typedef float  f32x4  __attribute__((ext_vector_type(4)));
typedef short  bf16x8 __attribute__((ext_vector_type(8)));

__device__ __forceinline__ float sigmoid_f(float x) {
    return 1.0f / (1.0f + expf(-x));
}

__device__ __forceinline__ unsigned short bf16_rne(float x) {
    union { float f; unsigned u; } c; c.f = x;
    unsigned u = c.u + 0x7fffu + ((c.u >> 16) & 1u);
    return (unsigned short)(u >> 16);
}

// ---------------------------------------------------------------- kernel A --
__global__ __launch_bounds__(256) void coarse_mlp_kernel(
    const float* __restrict__ coarse_W,
    const float* __restrict__ W1,
    const float* __restrict__ b1,
    float* __restrict__ hc,
    int nCoarse)
{
    const int t = blockIdx.x * 256 + threadIdx.x;
    if (t >= nCoarse * HH) return;
    const int r = t >> 5;
    const int j = t & 31;
    const float* __restrict__ row = coarse_W + (size_t)r * DD;
    const float* __restrict__ w   = W1 + DD * HH + j;   // coarse rows of W1
    float acc = b1[j];
    #pragma unroll 8
    for (int i = 0; i < DD; ++i)
        acc = fmaf(row[i], w[i * HH], acc);
    hc[t] = acc;
}

// ---------------------------------------------------------------- kernel B --
__global__ __launch_bounds__(256, 4) void fused_kernel(
    const int*   __restrict__ fine_ids,
    const int*   __restrict__ coarse_ids,
    const float* __restrict__ fine_W,
    const float* __restrict__ coarse_W,
    const float* __restrict__ freq_W,
    const float* __restrict__ W1,
    const float* __restrict__ W2,
    const float* __restrict__ b2,
    const float* __restrict__ hc,
    float* __restrict__ out_fused,
    float* __restrict__ out_gate)
{
    __shared__ __align__(16) unsigned int sX[4][1024];  // 4KB per wave, private
    __shared__ float s_fw[256];
    __shared__ int   s_if[256];
    __shared__ int   s_ic[256];

    const int tid  = threadIdx.x;
    const int lane = tid & 63;
    const int wave = tid >> 6;
    const int P0   = (int)blockIdx.x * 256;

    const int jlo = lane & 15;
    const int kg  = lane >> 4;          // 0..3

    // ---- metadata (each wave writes & later reads ONLY its own 64 slots) --
    {
        const int p = P0 + tid;
        const int idf = fine_ids[p];
        s_if[tid] = idf;
        s_ic[tid] = coarse_ids[p];
        s_fw[tid] = sigmoid_f(freq_W[idf]);
    }

    // ---- W1 fine-half B-fragments -> 32 VGPRs, held all kernel ----------
    bf16x8 bfr[2][4];
    #pragma unroll
    for (int n = 0; n < 2; ++n)
        #pragma unroll
        for (int ks = 0; ks < 4; ++ks)
            #pragma unroll
            for (int i = 0; i < 8; ++i) {
                const int k = ks * 32 + kg * 8 + i;
                bfr[n][ks][i] = (short)bf16_rne(W1[k * HH + jlo + 16 * n]);
            }

    // per-lane epilogue constants
    const float w256_0 = W1[2 * DD * HH + jlo];
    const float w256_1 = W1[2 * DD * HH + jlo + 16];
    const float W2_0   = W2[jlo];
    const float W2_1   = W2[jlo + 16];
    const float b2v    = b2[0];

    char* const swave = (char*)&sX[wave][0];
    const int wbase = wave * 64;        // wave's first local position

    // ---- main loop: 4 tiles of 16 rows, fully wave-independent ----------
    #pragma unroll 1
    for (int it = 0; it < 4; ++it) {
        const int base = wbase + it * 16;

        // 1. load 16 fine rows, f32, coalesced (64 lanes x float2 = 512B row)
        float2 rv[16];
        #pragma unroll
        for (int i = 0; i < 16; ++i) {
            const int idf = s_if[base + i];
            rv[i] = *(const float2*)(fine_W + (size_t)idf * DD + 2 * lane);
        }

        // 2. bf16-pack + swizzled ds_write into the wave-private region
        #pragma unroll
        for (int i = 0; i < 16; ++i) {
            const unsigned pk = (unsigned)bf16_rne(rv[i].x)
                              | ((unsigned)bf16_rne(rv[i].y) << 16);
            *(unsigned*)(swave + i * 256 + ((4 * lane) ^ ((i & 7) << 4))) = pk;
        }

        // 3. MFMA: X(16x128) @ W1fine(128x32)
        f32x4 acc0 = {0.f, 0.f, 0.f, 0.f};
        f32x4 acc1 = {0.f, 0.f, 0.f, 0.f};
        #pragma unroll
        for (int ks = 0; ks < 4; ++ks) {
            const bf16x8 a = *(const bf16x8*)(swave
                + jlo * 256 + ((kg * 16 + ks * 64) ^ ((jlo & 7) << 4)));
            acc0 = __builtin_amdgcn_mfma_f32_16x16x32_bf16(a, bfr[0][ks], acc0, 0, 0, 0);
            acc1 = __builtin_amdgcn_mfma_f32_16x16x32_bf16(a, bfr[1][ks], acc1, 0, 0, 0);
        }

        // 4. epilogue: + hc + freq row, relu, @W2, butterfly, sigmoid
        float adjv[4];
        #pragma unroll
        for (int r = 0; r < 4; ++r) {
            const int posl = base + kg * 4 + r;
            const int idc  = s_ic[posl];
            const float fw = s_fw[posl];
            const float* __restrict__ hcrow = hc + idc * HH;
            const float v0 = acc0[r] + hcrow[jlo]      + w256_0 * fw;
            const float v1 = acc1[r] + hcrow[jlo + 16] + w256_1 * fw;
            float tr = fmaxf(v0, 0.f) * W2_0 + fmaxf(v1, 0.f) * W2_1;
            tr += __shfl_xor(tr, 1);
            tr += __shfl_xor(tr, 2);
            tr += __shfl_xor(tr, 4);
            tr += __shfl_xor(tr, 8);
            adjv[r] = sigmoid_f(tr + b2v) * fw;       // uniform across jlo group
            if (jlo == r)
                __builtin_nontemporal_store(adjv[r], out_gate + P0 + posl);
        }

        // 5. blend from rv (exact f32) + coarse gather, nt store
        #pragma unroll
        for (int i = 0; i < 16; ++i) {
            const float a = __shfl(adjv[i & 3], ((i >> 2) << 4) + (i & 3));
            const int idc = s_ic[base + i];
            const float2 c2 = *(const float2*)(coarse_W + (size_t)idc * DD + 2 * lane);
            f32x2 o;
            o.x = fmaf(a, rv[i].x - c2.x, c2.x);
            o.y = fmaf(a, rv[i].y - c2.y, c2.y);
            f32x2* dst = (f32x2*)(out_fused + (size_t)(P0 + base + i) * DD + 2 * lane);
            __builtin_nontemporal_store(o, dst);      // 512B/row, coalesced
        }
    }
}

// ------------------------------------------------------------------- launch --
extern "C" void kernel_launch(void* const* d_in, const int* in_sizes, int n_in,
                              void* d_out, int out_size, void* d_ws, size_t ws_size,
                              hipStream_t stream) {
    const int*   fine_ids   = (const int*)  d_in[0];
    const int*   coarse_ids = (const int*)  d_in[1];
    const float* fine_W     = (const float*)d_in[2];
    const float* coarse_W   = (const float*)d_in[3];
    const float* freq_W     = (const float*)d_in[4];
    const float* W1         = (const float*)d_in[5];
    const float* b1         = (const float*)d_in[6];
    const float* W2         = (const float*)d_in[7];
    const float* b2         = (const float*)d_in[8];

    const int n       = in_sizes[0];          // B*L = 409600 (divisible by 256)
    const int nCoarse = in_sizes[3] / DD;     // 10001

    float* out_fused = (float*)d_out;
    float* out_gate  = (float*)d_out + (size_t)n * DD;
    float* hc        = (float*)d_ws;          // nCoarse*32 floats = 1.28 MB

    coarse_mlp_kernel<<<dim3((nCoarse * HH + 255) / 256), dim3(256), 0, stream>>>(
        coarse_W, W1, b1, hc, nCoarse);

    fused_kernel<<<dim3(n / 256), dim3(256), 0, stream>>>(
        fine_ids, coarse_ids, fine_W, coarse_W, freq_W,
        W1, W2, b2, hc, out_fused, out_gate);
}